// Round 16
// baseline (425.880 us; speedup 1.0000x reference)
//
#include <hip/hip_runtime.h>
#include <hip/hip_bf16.h>
#include <cstdint>
#include <cstddef>

typedef float f4 __attribute__((ext_vector_type(4)));
typedef short s16x8 __attribute__((ext_vector_type(8)));   // 8 bf16 in 4 VGPRs
typedef short s16x4 __attribute__((ext_vector_type(4)));

#define N_NODES 2048
#define BATCH 16
#define LSEQ 12
#define MDIM 112
#define GDIM 448                   // 4*M
#define KC 35                      // reduced contraction: 3 hist + 16 tid + 16 diw
#define NCOLS_X 6784               // logical GEMM cols: 6720 real + na/rs pad
#define NREAL (KC*BATCH*LSEQ)      // 6720 real feature cols
#define NA_HI 6720                 // cols 6720..6735: hi(node_emb[:,e])
#define NA_LO 6736                 // cols 6736..6751: lo(node_emb[:,e])
#define RS_COL 6752                // col 6752: ones
#define FSLOT 48                   // XAfrag row slice: 0..34 hi, 35..37 lo(hist), 38..40 hi(hist)
#define KBIG 2048                  // hi-only bf16
#define KL 64                      // lstm gates contraction
#define WTB_SH (GDIM * KL)         // 28672 shorts = 57344 B

#define GLDS16(SRC, DST)                                                        \
    __builtin_amdgcn_global_load_lds(                                           \
        (const __attribute__((address_space(1))) void*)(SRC),                   \
        (__attribute__((address_space(3))) void*)(DST), 16, 0, 0)

#define MFMA16(ACC, AV, BV) \
    ACC = __builtin_amdgcn_mfma_f32_16x16x32_bf16(AV, BV, ACC, 0, 0, 0)

__device__ __forceinline__ short bf16hi(float v) {
    union { __hip_bfloat16 h; short s; } u;
    u.h = __float2bfloat16(v);
    return u.s;
}
__device__ __forceinline__ short bf16lo(float v) {
    union { __hip_bfloat16 h; short s; } u;
    u.h = __float2bfloat16(v);
    float r = v - __bfloat162float(u.h);
    u.h = __float2bfloat16(r);
    return u.s;
}
// native-rate activations (v_exp + v_rcp): IEEE fp32 div expands to ~10 VALU
// insts and made lstm VALU-bound (R10).
__device__ __forceinline__ float rcpf_(float x)  { return __builtin_amdgcn_rcpf(x); }
__device__ __forceinline__ float sigf_(float x)  { return rcpf_(1.0f + __expf(-x)); }
__device__ __forceinline__ float tanhf_(float x) { return 1.0f - 2.0f * rcpf_(1.0f + __expf(2.0f * x)); }

// ---------------------------------------------------------------------------
// K1: A_dy = softmax(relu(E @ E^T), axis=1) -> bf16 rows of Abig[2048+n].
// ---------------------------------------------------------------------------
__global__ void adaptive_adj_kernel(const float* __restrict__ E,
                                    __hip_bfloat16* __restrict__ Abig)
{
    __shared__ float sbuf[N_NODES];
    __shared__ float red[256];
    const int n = blockIdx.x;
    const int tid = threadIdx.x;
    float en[16];
#pragma unroll
    for (int i = 0; i < 16; ++i) en[i] = E[n * 16 + i];
    float lmax = -3.4e38f;
    for (int k = tid; k < N_NODES; k += 256) {
        const float* ek = E + k * 16;
        float d = 0.f;
#pragma unroll
        for (int i = 0; i < 16; ++i) d += en[i] * ek[i];
        d = fmaxf(d, 0.0f);
        sbuf[k] = d;
        lmax = fmaxf(lmax, d);
    }
    red[tid] = lmax; __syncthreads();
    for (int s = 128; s > 0; s >>= 1) {
        if (tid < s) red[tid] = fmaxf(red[tid], red[tid + s]);
        __syncthreads();
    }
    float mx = red[0];
    __syncthreads();
    float lsum = 0.f;
    for (int k = tid; k < N_NODES; k += 256) {
        float e = __expf(sbuf[k] - mx);
        sbuf[k] = e;
        lsum += e;
    }
    red[tid] = lsum; __syncthreads();
    for (int s = 128; s > 0; s >>= 1) {
        if (tid < s) red[tid] += red[tid + s];
        __syncthreads();
    }
    float rinv = rcpf_(red[0]);
    __syncthreads();

    __hip_bfloat16* arow = Abig + (size_t)(2048 + n) * KBIG;
    for (int k = tid; k < N_NODES; k += 256)
        arow[k] = __float2bfloat16(sbuf[k] * rinv);
}

// ---------------------------------------------------------------------------
// K2: SELF-CONTAINED gate-weight pack (both layers, one dispatch), bf16,
// PRE-SWIZZLED for the lstm's ds_read side.
// ---------------------------------------------------------------------------
__global__ void wtb_pack_kernel(const float* __restrict__ W_in,
                                const float* __restrict__ b_in,
                                const float* __restrict__ Wp,
                                const float* __restrict__ bp,
                                const float* __restrict__ Wd,
                                const float* __restrict__ bd,
                                short* __restrict__ outp)
{
    int idx = blockIdx.x * 256 + threadIdx.x;      // z*GDIM*KL + r*64 + p
    if (idx >= 2 * GDIM * KL) return;
    int z = idx >= GDIM * KL;
    int rem = idx - z * GDIM * KL;
    const float* W  = z ? Wd : Wp;
    const float* bg = z ? bd : bp;
    int p = rem & 63;
    int r = rem >> 6;
    int tile = r >> 4, gc = r & 15;
    int mi = tile >> 2, co = tile & 3;
    int g = co * 112 + mi * 16 + gc;

    float v = 0.f; bool lo = false; bool zero = false;
    #define DOTW(VEC) ({ float s_ = 0.f;                                     \
        for (int m = 0; m < 64; ++m) s_ += (VEC)[m] * W[(size_t)m * GDIM + g];\
        s_; })
    if (p < 3)         v = DOTW(W_in + p * 64);
    else if (p < 35)   v = W[(size_t)(80 + p - 3) * GDIM + g];
    else if (p < 38)   v = DOTW(W_in + (p - 35) * 64);
    else if (p < 41) { v = DOTW(W_in + (p - 38) * 64); lo = true; }
    else if (p == 41)  v = bg[g];
    else if (p == 42)  v = DOTW(b_in);
    else if (p < 59)   v = W[(size_t)(64 + p - 43) * GDIM + g];
    else if (p == 59) { v = bg[g]; lo = true; }
    else if (p == 60) { v = DOTW(b_in); lo = true; }
    else zero = true;
    #undef DOTW
    short s = zero ? (short)0 : (lo ? bf16lo(v) : bf16hi(v));
    int a = r * 128 + p * 2;
    int asw = a ^ (((a >> 7) & 7) << 4);
    outp[(size_t)z * WTB_SH + (asw >> 1)] = s;
}

// ---------------------------------------------------------------------------
// K3: merged pack: predefined-adjacency bf16 rows of Abig AND transposed
// hi-only XT (features + na/rs columns), one dispatch, 4-wide per thread.
// ---------------------------------------------------------------------------
#define AQUADS (2048 * 2048 / 4)
#define XQUADS (NCOLS_X * 2048 / 4)
__global__ void pack_build_kernel(const float* __restrict__ adj,
                                  const float* __restrict__ hist,
                                  const float* __restrict__ tid_emb,
                                  const float* __restrict__ diw_emb,
                                  const float* __restrict__ node_emb,
                                  __hip_bfloat16* __restrict__ Abig,
                                  __hip_bfloat16* __restrict__ XT)
{
    int idx = blockIdx.x * 256 + threadIdx.x;
    if (idx < AQUADS) {
        int e0 = idx << 2;
        int k = e0 & 2047;
        int m = e0 >> 11;                            // 0..2047
        f4 v = *(const f4*)(adj + (size_t)m * 2048 + k);
        s16x4 o = { bf16hi(v[0]), bf16hi(v[1]), bf16hi(v[2]), bf16hi(v[3]) };
        *(s16x4*)((short*)Abig + (size_t)m * KBIG + k) = o;
        return;
    }
    int xi = idx - AQUADS;
    if (xi >= XQUADS) return;
    int e0 = xi << 2;
    int k0 = e0 & 2047;
    int jl = e0 >> 11;
    s16x4 o = {0, 0, 0, 0};
    if (jl < NREAL) {
        int c = jl % KC;
        int bl = jl / KC;
#pragma unroll
        for (int i = 0; i < 4; ++i) {
            const float* h = hist + ((size_t)(bl * N_NODES + k0 + i)) * 3;
            float v;
            if (c < 3) v = h[c];
            else if (c < 19) { int ti = (int)(h[1] * 288.0f); v = tid_emb[ti * 16 + (c - 3)]; }
            else             { int di = (int)(h[2] * 7.0f);   v = diw_emb[di * 16 + (c - 19)]; }
            o[i] = bf16hi(v);
        }
    } else if (jl >= NA_HI && jl < NA_LO) {          // hi(node_emb[:,e])
        int e = jl - NA_HI;
#pragma unroll
        for (int i = 0; i < 4; ++i) o[i] = bf16hi(node_emb[(k0 + i) * 16 + e]);
    } else if (jl >= NA_LO && jl < RS_COL) {         // lo(node_emb[:,e])
        int e = jl - NA_LO;
#pragma unroll
        for (int i = 0; i < 4; ++i) o[i] = bf16lo(node_emb[(k0 + i) * 16 + e]);
    } else if (jl == RS_COL) {                       // ones -> rs
        short one = bf16hi(1.0f);
        o[0] = one; o[1] = one; o[2] = one; o[3] = one;
    }
    *(s16x4*)((short*)XT + (size_t)jl * KBIG + k0) = o;
}

// ---------------------------------------------------------------------------
// K4: bf16 MFMA GEMM, BK=64, 2-barrier, both-sides XOR swizzle (R14 proven).
// Epilogue writes FRAGMENT-READY XAfrag[(r>>7)*192+bt][row&127][48]:
// slot c = hi, 35+c = lo(hist), 38+c = hi(hist dup) — so the lstm can load
// its MFMA A-operand 16B-chunks straight from global (no LDS staging).
// na/rs padding columns -> fp32 arrays (unchanged from R15).
// ---------------------------------------------------------------------------
__global__ __launch_bounds__(512, 4) void gemm_bf16_kernel(const short* __restrict__ A,
                                                           const short* __restrict__ BT,
                                                           short* __restrict__ XAfrag,
                                                           float* __restrict__ na_pre,
                                                           float* __restrict__ na_dy,
                                                           float* __restrict__ rs_pre,
                                                           float* __restrict__ rs_dy)
{
    __shared__ short As[256 * 64];     // 32 KB, 128 B/row, swizzled
    __shared__ short Bs[128 * 64];     // 16 KB
    const int tid = threadIdx.x;
    const int w = tid >> 6;            // wave 0..7
    const int l = tid & 63;
    const int wr = w >> 1;             // 0..3 -> 64-row band
    const int wc = w & 1;              // 0..1 -> 64-col band
    const int lm = l & 15;

    const int bid = blockIdx.y * 53 + blockIdx.x;        // 0..847
    const int sid = (bid & 7) * 106 + (bid >> 3);        // XCD-contiguous
    const int col = sid >> 4;                            // 0..52 (column-major)
    const int row = sid & 15;                            // 0..15
    const int m0 = row * 256;
    const int jt = col * 128;

    const int srow = tid >> 3;                           // 0..63
    const int koct = (tid & 7) ^ (srow & 7);
    const size_t gA = (size_t)(m0 + srow) * KBIG + koct * 8;
    const size_t gB = (size_t)(jt + srow) * KBIG + koct * 8;
    char* lA = (char*)As + srow * 128 + (tid & 7) * 16;
    char* lB = (char*)Bs + srow * 128 + (tid & 7) * 16;

    f4 acc[4][4];
#pragma unroll
    for (int i = 0; i < 4; ++i)
#pragma unroll
        for (int j = 0; j < 4; ++j)
#pragma unroll
            for (int e = 0; e < 4; ++e) acc[i][j][e] = 0.f;

    const int sm  = (l & 7) << 4;       // read-side swizzle key
    const int k16 = (l >> 4) * 16;

    for (int kt = 0; kt < KBIG; kt += 64) {
        __syncthreads();
        GLDS16(A  + gA + kt,                      lA);
        GLDS16(A  + gA + kt + (size_t)64  * KBIG, lA + 64  * 128);
        GLDS16(A  + gA + kt + (size_t)128 * KBIG, lA + 128 * 128);
        GLDS16(A  + gA + kt + (size_t)192 * KBIG, lA + 192 * 128);
        GLDS16(BT + gB + kt,                      lB);
        GLDS16(BT + gB + kt + (size_t)64  * KBIG, lB + 64  * 128);
        __syncthreads();
#pragma unroll
        for (int ks = 0; ks < 2; ++ks) {
            const int ko = (ks * 64 + k16) ^ sm;
            s16x8 a[4], b[4];
#pragma unroll
            for (int mi = 0; mi < 4; ++mi)
                a[mi] = *(const s16x8*)((const char*)As + (wr * 64 + mi * 16 + lm) * 128 + ko);
#pragma unroll
            for (int ni = 0; ni < 4; ++ni)
                b[ni] = *(const s16x8*)((const char*)Bs + (wc * 64 + ni * 16 + lm) * 128 + ko);
#pragma unroll
            for (int mi = 0; mi < 4; ++mi)
#pragma unroll
                for (int ni = 0; ni < 4; ++ni)
                    MFMA16(acc[mi][ni], a[mi], b[ni]);
        }
    }

    const int rbase = m0 + wr * 64 + (l >> 4) * 4;
    const int cbase = jt + wc * 64 + lm;
#pragma unroll
    for (int mi = 0; mi < 4; ++mi)
#pragma unroll
        for (int ni = 0; ni < 4; ++ni) {
            int cc = cbase + ni * 16;
            if (cc < NREAL) {
                int bt = cc / KC;
                int c  = cc - bt * KC;
#pragma unroll
                for (int reg = 0; reg < 4; ++reg) {
                    int r = rbase + mi * 16 + reg;
                    size_t fr = (((size_t)(r >> 7) * 192 + bt) * 128 + (r & 127)) * FSLOT;
                    float v = acc[mi][ni][reg];
                    short hv = bf16hi(v);
                    XAfrag[fr + c] = hv;
                    if (c < 3) {
                        XAfrag[fr + 35 + c] = bf16lo(v);
                        XAfrag[fr + 38 + c] = hv;     // dup for the k38..40 cross term
                    }
                }
            }
        }

    // na/rs epilogue: block-col 52, wc=1 lanes hold cols 6720+lm (hi, ni=0),
    // 6736+lm (lo, ni=1), 6752+lm (ones, ni=2; real only for lm==0).
    if (jt == 6656 && wc == 1) {
#pragma unroll
        for (int mi = 0; mi < 4; ++mi)
#pragma unroll
            for (int reg = 0; reg < 4; ++reg) {
                int r = rbase + mi * 16 + reg;
                float nav = acc[mi][0][reg] + acc[mi][1][reg];
                int rr = r & 2047;
                if (r < 2048) {
                    na_pre[rr * 16 + lm] = nav;
                    if (lm == 0) rs_pre[rr] = acc[mi][2][reg];
                } else {
                    na_dy[rr * 16 + lm] = nav;
                    if (lm == 0) rs_dy[rr] = acc[mi][2][reg];
                }
            }
    }
}

// ---------------------------------------------------------------------------
// K5: fused MFMA gates + LSTM c-recurrence, v7: ZERO LDS staging for Xa.
// Each lane loads its MFMA A-operand 16B-chunks directly from XAfrag
// (fragment-ready layout), and holds the per-node constant k-slots
// (na/rs/1.0, k>=41) in registers built once.  No barriers in the t-loop.
// Values and MFMA order identical to lstm6 -> bit-exact.
// ---------------------------------------------------------------------------
__global__ __launch_bounds__(512, 4) void lstm7_kernel(
    const short* __restrict__ XAfrag,
    const short* __restrict__ WtBg,            // [2][WTB_SH] pre-swizzled
    const float* __restrict__ na_pre, const float* __restrict__ na_dy,
    const float* __restrict__ rs_pre, const float* __restrict__ rs_dy,
    float* __restrict__ H)
{
    __shared__ short sWtb[WTB_SH];             // 57344 B (only LDS use)
    const int tid = threadIdx.x;
    const int w = tid >> 6, l = tid & 63;      // 8 waves
    const int nb = blockIdx.x;                 // 0..15 (128-node block)
    const int b  = blockIdx.y;
    const int z  = blockIdx.z;
    const float* na = z ? na_dy : na_pre;
    const float* rs = z ? rs_dy : rs_pre;

    // stage WtB via global_load_lds: 3584 16B-chunks = 8 waves x 7 iters
    {
        const char* gW = (const char*)(WtBg + (size_t)z * WTB_SH);
        char* lW = (char*)sWtb;
        for (int it = 0; it < 7; ++it) {
            int base = (it * 8 + w) * 64;
            GLDS16(gW + (size_t)(base + l) * 16, lW + base * 16);
        }
    }

    const int lm = l & 15;
    const int gr = l >> 4;                     // k-group 0..3
    const int an = w * 16 + lm;                // node row within block
    const int gn = nb * 128 + an;              // node index

    // per-node constant k-slots (k41..63), built once in registers:
    short cna[16];
#pragma unroll
    for (int e = 0; e < 16; ++e) cna[e] = bf16hi(na[gn * 16 + e]);
    const short c1  = bf16hi(1.0f);
    const short crs = bf16hi(rs[gn]);
    s16x8 a1c = {0, 0, 0, 0, 0, 0, 0, 0};
    if (gr == 1) {        // k40..47: [hi2(loaded), 1.0, rs, na0..na4]
        a1c[1] = c1; a1c[2] = crs;
        a1c[3] = cna[0]; a1c[4] = cna[1]; a1c[5] = cna[2];
        a1c[6] = cna[3]; a1c[7] = cna[4];
    } else if (gr == 2) { // k48..55: na5..na12
        a1c[0] = cna[5];  a1c[1] = cna[6];  a1c[2] = cna[7];  a1c[3] = cna[8];
        a1c[4] = cna[9];  a1c[5] = cna[10]; a1c[6] = cna[11]; a1c[7] = cna[12];
    } else if (gr == 3) { // k56..63: [na13, na14, na15, 1.0, rs, 0, 0, 0]
        a1c[0] = cna[13]; a1c[1] = cna[14]; a1c[2] = cna[15];
        a1c[3] = c1; a1c[4] = crs;
    }

    // per-lane global source: row slice = base + t*128*48 + an*48
    const short* xaf = XAfrag + (((size_t)(z * 16 + nb) * 16 + b) * 12) * (128 * FSLOT)
                     + an * FSLOT;
    const int off1 = (gr == 0) ? 32 : 40;      // a1 load offset (slots)

    const int sm = (l & 7) << 4;
    const int kof0 = ((l >> 4) * 16) ^ sm;
    const int kof1 = (64 + (l >> 4) * 16) ^ sm;
    const char* wtbb = (const char*)sWtb;
    float* Hout = H + (size_t)z * BATCH * N_NODES * MDIM;

    float cc[7][4];
#pragma unroll
    for (int mi = 0; mi < 7; ++mi)
#pragma unroll
        for (int q = 0; q < 4; ++q) cc[mi][q] = 0.f;

    // prefetch t = 0
    s16x8 pa0 = *(const s16x8*)(xaf + gr * 8);
    s16x8 pL  = *(const s16x8*)(xaf + off1);

    __syncthreads();     // WtB DMA drained (vmcnt+barrier)

    for (int t = 0; t < LSEQ; ++t) {
        s16x8 a0 = pa0;
        s16x8 a1;
        if (gr == 0) a1 = pL;
        else { a1 = a1c; if (gr == 1) a1[0] = pL[0]; }

        // prefetch t+1 — hides under this t's MFMA + activations
        if (t + 1 < LSEQ) {
            const short* sl = xaf + (size_t)(t + 1) * (128 * FSLOT);
            pa0 = *(const s16x8*)(sl + gr * 8);
            pL  = *(const s16x8*)(sl + off1);
        }

#pragma unroll
        for (int mi = 0; mi < 7; ++mi) {
            const char* bb = wtbb + (mi * 64 + lm) * 128;   // co=0 row; co step = +2048B
            f4 gi = {0.f, 0.f, 0.f, 0.f};
            f4 gf = gi, gg = gi;
            MFMA16(gi, a0, *(const s16x8*)(bb + kof0));
            MFMA16(gi, a1, *(const s16x8*)(bb + kof1));
            MFMA16(gf, a0, *(const s16x8*)(bb + 2048 + kof0));
            MFMA16(gf, a1, *(const s16x8*)(bb + 2048 + kof1));
            MFMA16(gg, a0, *(const s16x8*)(bb + 4096 + kof0));
            MFMA16(gg, a1, *(const s16x8*)(bb + 4096 + kof1));
#pragma unroll
            for (int q = 0; q < 4; ++q) {
                float si = sigf_(gi[q]);
                float sf = sigf_(gf[q]);
                float tg = tanhf_(gg[q]);
                cc[mi][q] = sf * cc[mi][q] + si * tg;
            }
            if (t == LSEQ - 1) {
                f4 go = {0.f, 0.f, 0.f, 0.f};
                MFMA16(go, a0, *(const s16x8*)(bb + 6144 + kof0));
                MFMA16(go, a1, *(const s16x8*)(bb + 6144 + kof1));
#pragma unroll
                for (int q = 0; q < 4; ++q) {
                    float h = sigf_(go[q]) * tanhf_(cc[mi][q]);
                    Hout[((size_t)b * N_NODES + nb * 128 + w * 16 + (l >> 4) * 4 + q) * MDIM
                         + mi * 16 + lm] = h;
                }
            }
        }
    }
}

// ---------------------------------------------------------------------------
// K6: fused decoder, f4-vectorized H loads.
// ---------------------------------------------------------------------------
__global__ void decode_kernel(const float* __restrict__ H,
                              const float* __restrict__ Wdec,
                              const float* __restrict__ bdec,
                              const float* __restrict__ Wout,
                              const float* __restrict__ bout,
                              float* __restrict__ out)
{
    int g = blockIdx.x * 256 + threadIdx.x;   // g = b*2048 + n
    if (g >= BATCH * N_NODES) return;
    int b = g >> 11;
    int n = g & 2047;
    const f4* h0 = (const f4*)(H + (size_t)g * MDIM);
    const f4* h1 = (const f4*)(H + (size_t)BATCH * N_NODES * MDIM + (size_t)g * MDIM);
    float x[12];
#pragma unroll
    for (int o = 0; o < 12; ++o) x[o] = bdec[o];
    for (int mq = 0; mq < 28; ++mq) {
        f4 a0 = h0[mq], a1 = h1[mq];
#pragma unroll
        for (int e = 0; e < 4; ++e) {
            int m = mq * 4 + e;
#pragma unroll
            for (int o = 0; o < 12; ++o)
                x[o] += a0[e] * Wdec[(o * 3 + 0) * MDIM + m]
                      + a1[e] * (Wdec[(o * 3 + 1) * MDIM + m] + Wdec[(o * 3 + 2) * MDIM + m]);
        }
    }
#pragma unroll
    for (int p = 0; p < 12; ++p) {
        float s = bout[p];
#pragma unroll
        for (int o = 0; o < 12; ++o) s += Wout[p * 12 + o] * x[o];
        out[((size_t)b * 12 + p) * N_NODES + n] = s;
    }
}

// ---------------------------------------------------------------------------
extern "C" void kernel_launch(void* const* d_in, const int* in_sizes, int n_in,
                              void* d_out, int out_size, void* d_ws, size_t ws_size,
                              hipStream_t stream)
{
    const float* hist   = (const float*)d_in[0];
    const float* adj    = (const float*)d_in[1];
    const float* node_e = (const float*)d_in[2];
    const float* tid_e  = (const float*)d_in[3];
    const float* diw_e  = (const float*)d_in[4];
    const float* W_in   = (const float*)d_in[5];
    const float* b_in   = (const float*)d_in[6];
    const float* W_pre  = (const float*)d_in[7];
    const float* b_pre  = (const float*)d_in[8];
    const float* E_dy   = (const float*)d_in[9];
    const float* W_dy   = (const float*)d_in[10];
    const float* b_dy   = (const float*)d_in[11];
    const float* W_dec  = (const float*)d_in[12];
    const float* b_dec  = (const float*)d_in[13];
    const float* W_out  = (const float*)d_in[14];
    const float* b_out  = (const float*)d_in[15];
    float* out = (float*)d_out;

    float* ws = (float*)d_ws;
    const size_t XAF_F  = (size_t)4096 * 192 * FSLOT / 2;    // 18,874,368 float-equiv
    const size_t ABIG_F = (size_t)4096 * KBIG / 2;           //  4,194,304 float-equiv
    const size_t XT_F   = (size_t)NCOLS_X * KBIG / 2;        //  6,946,816 float-equiv

    short* XAfrag = (short*)ws;               // [32][192][128][48] bf16
    float* AbigF = ws + XAF_F;
    __hip_bfloat16* Abig = (__hip_bfloat16*)AbigF;
    float* H     = AbigF;                     // aliases Abig+XT (dead after gemm); 7.34M < 11.1M
    __hip_bfloat16* XTc = (__hip_bfloat16*)(ws + XAF_F + ABIG_F);
    float* tail = ws + XAF_F + ABIG_F + XT_F;
    float* na_pre = tail;                     tail += (size_t)N_NODES * 16;
    float* na_dy  = tail;                     tail += (size_t)N_NODES * 16;
    float* rs_pre = tail;                     tail += N_NODES;
    float* rs_dy  = tail;                     tail += N_NODES;
    short* WtBg   = (short*)tail;             // 2 * WTB_SH shorts

    // dynamic adjacency rows go straight into Abig (bf16)
    adaptive_adj_kernel<<<N_NODES, 256, 0, stream>>>(E_dy, Abig);
    wtb_pack_kernel<<<(2 * GDIM * KL + 255) / 256, 256, 0, stream>>>(
        W_in, b_in, W_pre, b_pre, W_dy, b_dy, WtBg);

    // predefined-adjacency half of Abig + full XT (features + na/rs cols)
    pack_build_kernel<<<(AQUADS + XQUADS + 255) / 256, 256, 0, stream>>>(
        adj, hist, tid_e, diw_e, node_e, Abig, XTc);

    // ONE GEMM: fragment-ready XAfrag + na/rs (padding columns)
    gemm_bf16_kernel<<<dim3(53, 16), 512, 0, stream>>>(
        (const short*)Abig, (const short*)XTc, XAfrag, na_pre, na_dy, rs_pre, rs_dy);

    // fused MFMA gates + recurrence, barrier-free t-loop
    lstm7_kernel<<<dim3(16, BATCH, 2), 512, 0, stream>>>(
        XAfrag, WtBg, na_pre, na_dy, rs_pre, rs_dy, H);

    decode_kernel<<<(BATCH * N_NODES + 255) / 256, 256, 0, stream>>>(
        H, W_dec, b_dec, W_out, b_out, out);
}

// Round 17
// 283.082 us; speedup vs baseline: 1.5044x; 1.5044x over previous
//
#include <hip/hip_runtime.h>
#include <hip/hip_bf16.h>
#include <cstdint>
#include <cstddef>

typedef float f4 __attribute__((ext_vector_type(4)));
typedef short s16x8 __attribute__((ext_vector_type(8)));   // 8 bf16 in 4 VGPRs
typedef short s16x4 __attribute__((ext_vector_type(4)));

#define N_NODES 2048
#define BATCH 16
#define LSEQ 12
#define MDIM 112
#define GDIM 448                   // 4*M
#define KC 35                      // reduced contraction: 3 hist + 16 tid + 16 diw
#define NCOLS_X 6784               // logical GEMM cols: 6720 real + na/rs pad
#define NREAL (KC*BATCH*LSEQ)      // 6720 real feature cols
#define NA_HI 6720                 // cols 6720..6735: hi(node_emb[:,e])
#define NA_LO 6736                 // cols 6736..6751: lo(node_emb[:,e])
#define RS_COL 6752                // col 6752: ones
#define XROW 7680                  // XAhi row: 192 (b,t)-slices x 40 shorts (0..34 hi, 36..38 lo)
#define KBIG 2048                  // hi-only bf16
#define KL 64                      // lstm gates contraction
#define WTB_SH (GDIM * KL)         // 28672 shorts = 57344 B

#define GLDS16(SRC, DST)                                                        \
    __builtin_amdgcn_global_load_lds(                                           \
        (const __attribute__((address_space(1))) void*)(SRC),                   \
        (__attribute__((address_space(3))) void*)(DST), 16, 0, 0)

#define MFMA16(ACC, AV, BV) \
    ACC = __builtin_amdgcn_mfma_f32_16x16x32_bf16(AV, BV, ACC, 0, 0, 0)

__device__ __forceinline__ short bf16hi(float v) {
    union { __hip_bfloat16 h; short s; } u;
    u.h = __float2bfloat16(v);
    return u.s;
}
__device__ __forceinline__ short bf16lo(float v) {
    union { __hip_bfloat16 h; short s; } u;
    u.h = __float2bfloat16(v);
    float r = v - __bfloat162float(u.h);
    u.h = __float2bfloat16(r);
    return u.s;
}
// native-rate activations (v_exp + v_rcp): IEEE fp32 div expands to ~10 VALU
// insts and made lstm VALU-bound (R10).
__device__ __forceinline__ float rcpf_(float x)  { return __builtin_amdgcn_rcpf(x); }
__device__ __forceinline__ float sigf_(float x)  { return rcpf_(1.0f + __expf(-x)); }
__device__ __forceinline__ float tanhf_(float x) { return 1.0f - 2.0f * rcpf_(1.0f + __expf(2.0f * x)); }

// ---------------------------------------------------------------------------
// K1: A_dy = softmax(relu(E @ E^T), axis=1) -> bf16 rows of Abig[2048+n].
// (na/rs computed by the GEMM's padding columns.)
// ---------------------------------------------------------------------------
__global__ void adaptive_adj_kernel(const float* __restrict__ E,
                                    __hip_bfloat16* __restrict__ Abig)
{
    __shared__ float sbuf[N_NODES];
    __shared__ float red[256];
    const int n = blockIdx.x;
    const int tid = threadIdx.x;
    float en[16];
#pragma unroll
    for (int i = 0; i < 16; ++i) en[i] = E[n * 16 + i];
    float lmax = -3.4e38f;
    for (int k = tid; k < N_NODES; k += 256) {
        const float* ek = E + k * 16;
        float d = 0.f;
#pragma unroll
        for (int i = 0; i < 16; ++i) d += en[i] * ek[i];
        d = fmaxf(d, 0.0f);
        sbuf[k] = d;
        lmax = fmaxf(lmax, d);
    }
    red[tid] = lmax; __syncthreads();
    for (int s = 128; s > 0; s >>= 1) {
        if (tid < s) red[tid] = fmaxf(red[tid], red[tid + s]);
        __syncthreads();
    }
    float mx = red[0];
    __syncthreads();
    float lsum = 0.f;
    for (int k = tid; k < N_NODES; k += 256) {
        float e = __expf(sbuf[k] - mx);
        sbuf[k] = e;
        lsum += e;
    }
    red[tid] = lsum; __syncthreads();
    for (int s = 128; s > 0; s >>= 1) {
        if (tid < s) red[tid] += red[tid + s];
        __syncthreads();
    }
    float rinv = rcpf_(red[0]);
    __syncthreads();

    __hip_bfloat16* arow = Abig + (size_t)(2048 + n) * KBIG;
    for (int k = tid; k < N_NODES; k += 256)
        arow[k] = __float2bfloat16(sbuf[k] * rinv);
}

// ---------------------------------------------------------------------------
// K2: SELF-CONTAINED gate-weight pack (both layers, one dispatch), bf16,
// PRE-SWIZZLED for the lstm's ds_read side.
// ---------------------------------------------------------------------------
__global__ void wtb_pack_kernel(const float* __restrict__ W_in,
                                const float* __restrict__ b_in,
                                const float* __restrict__ Wp,
                                const float* __restrict__ bp,
                                const float* __restrict__ Wd,
                                const float* __restrict__ bd,
                                short* __restrict__ outp)
{
    int idx = blockIdx.x * 256 + threadIdx.x;      // z*GDIM*KL + r*64 + p
    if (idx >= 2 * GDIM * KL) return;
    int z = idx >= GDIM * KL;
    int rem = idx - z * GDIM * KL;
    const float* W  = z ? Wd : Wp;
    const float* bg = z ? bd : bp;
    int p = rem & 63;
    int r = rem >> 6;
    int tile = r >> 4, gc = r & 15;
    int mi = tile >> 2, co = tile & 3;
    int g = co * 112 + mi * 16 + gc;

    float v = 0.f; bool lo = false; bool zero = false;
    #define DOTW(VEC) ({ float s_ = 0.f;                                     \
        for (int m = 0; m < 64; ++m) s_ += (VEC)[m] * W[(size_t)m * GDIM + g];\
        s_; })
    if (p < 3)         v = DOTW(W_in + p * 64);
    else if (p < 35)   v = W[(size_t)(80 + p - 3) * GDIM + g];
    else if (p < 38)   v = DOTW(W_in + (p - 35) * 64);
    else if (p < 41) { v = DOTW(W_in + (p - 38) * 64); lo = true; }
    else if (p == 41)  v = bg[g];
    else if (p == 42)  v = DOTW(b_in);
    else if (p < 59)   v = W[(size_t)(64 + p - 43) * GDIM + g];
    else if (p == 59) { v = bg[g]; lo = true; }
    else if (p == 60) { v = DOTW(b_in); lo = true; }
    else zero = true;
    #undef DOTW
    short s = zero ? (short)0 : (lo ? bf16lo(v) : bf16hi(v));
    int a = r * 128 + p * 2;
    int asw = a ^ (((a >> 7) & 7) << 4);
    outp[(size_t)z * WTB_SH + (asw >> 1)] = s;
}

// ---------------------------------------------------------------------------
// K3: merged pack: predefined-adjacency bf16 rows of Abig AND transposed
// hi-only XT (features + na/rs columns), one dispatch, 4-wide per thread.
// ---------------------------------------------------------------------------
#define AQUADS (2048 * 2048 / 4)
#define XQUADS (NCOLS_X * 2048 / 4)
__global__ void pack_build_kernel(const float* __restrict__ adj,
                                  const float* __restrict__ hist,
                                  const float* __restrict__ tid_emb,
                                  const float* __restrict__ diw_emb,
                                  const float* __restrict__ node_emb,
                                  __hip_bfloat16* __restrict__ Abig,
                                  __hip_bfloat16* __restrict__ XT)
{
    int idx = blockIdx.x * 256 + threadIdx.x;
    if (idx < AQUADS) {
        int e0 = idx << 2;
        int k = e0 & 2047;
        int m = e0 >> 11;                            // 0..2047
        f4 v = *(const f4*)(adj + (size_t)m * 2048 + k);
        s16x4 o = { bf16hi(v[0]), bf16hi(v[1]), bf16hi(v[2]), bf16hi(v[3]) };
        *(s16x4*)((short*)Abig + (size_t)m * KBIG + k) = o;
        return;
    }
    int xi = idx - AQUADS;
    if (xi >= XQUADS) return;
    int e0 = xi << 2;
    int k0 = e0 & 2047;
    int jl = e0 >> 11;
    s16x4 o = {0, 0, 0, 0};
    if (jl < NREAL) {
        int c = jl % KC;
        int bl = jl / KC;
#pragma unroll
        for (int i = 0; i < 4; ++i) {
            const float* h = hist + ((size_t)(bl * N_NODES + k0 + i)) * 3;
            float v;
            if (c < 3) v = h[c];
            else if (c < 19) { int ti = (int)(h[1] * 288.0f); v = tid_emb[ti * 16 + (c - 3)]; }
            else             { int di = (int)(h[2] * 7.0f);   v = diw_emb[di * 16 + (c - 19)]; }
            o[i] = bf16hi(v);
        }
    } else if (jl >= NA_HI && jl < NA_LO) {          // hi(node_emb[:,e])
        int e = jl - NA_HI;
#pragma unroll
        for (int i = 0; i < 4; ++i) o[i] = bf16hi(node_emb[(k0 + i) * 16 + e]);
    } else if (jl >= NA_LO && jl < RS_COL) {         // lo(node_emb[:,e])
        int e = jl - NA_LO;
#pragma unroll
        for (int i = 0; i < 4; ++i) o[i] = bf16lo(node_emb[(k0 + i) * 16 + e]);
    } else if (jl == RS_COL) {                       // ones -> rs
        short one = bf16hi(1.0f);
        o[0] = one; o[1] = one; o[2] = one; o[3] = one;
    }
    *(s16x4*)((short*)XT + (size_t)jl * KBIG + k0) = o;
}

// ---------------------------------------------------------------------------
// K4: bf16 MFMA GEMM, BK=64, 2-barrier, both-sides XOR swizzle (R14 proven:
// bank-conflict 0, MfmaUtil ~40).  Epilogue: feature cols -> XAhi (bf16 hi +
// 3 hist lo, padded [row][bt][40]); na/rs padding cols (block-col 52, wc=1)
// -> fp32 arrays (hi+lo summed in-register).
// ---------------------------------------------------------------------------
__global__ __launch_bounds__(512, 4) void gemm_bf16_kernel(const short* __restrict__ A,
                                                           const short* __restrict__ BT,
                                                           short* __restrict__ XAhi,
                                                           float* __restrict__ na_pre,
                                                           float* __restrict__ na_dy,
                                                           float* __restrict__ rs_pre,
                                                           float* __restrict__ rs_dy)
{
    __shared__ short As[256 * 64];     // 32 KB, 128 B/row, swizzled
    __shared__ short Bs[128 * 64];     // 16 KB
    const int tid = threadIdx.x;
    const int w = tid >> 6;            // wave 0..7
    const int l = tid & 63;
    const int wr = w >> 1;             // 0..3 -> 64-row band
    const int wc = w & 1;              // 0..1 -> 64-col band
    const int lm = l & 15;

    const int bid = blockIdx.y * 53 + blockIdx.x;        // 0..847
    const int sid = (bid & 7) * 106 + (bid >> 3);        // XCD-contiguous
    const int col = sid >> 4;                            // 0..52 (column-major)
    const int row = sid & 15;                            // 0..15
    const int m0 = row * 256;
    const int jt = col * 128;

    const int srow = tid >> 3;                           // 0..63
    const int koct = (tid & 7) ^ (srow & 7);
    const size_t gA = (size_t)(m0 + srow) * KBIG + koct * 8;
    const size_t gB = (size_t)(jt + srow) * KBIG + koct * 8;
    char* lA = (char*)As + srow * 128 + (tid & 7) * 16;
    char* lB = (char*)Bs + srow * 128 + (tid & 7) * 16;

    f4 acc[4][4];
#pragma unroll
    for (int i = 0; i < 4; ++i)
#pragma unroll
        for (int j = 0; j < 4; ++j)
#pragma unroll
            for (int e = 0; e < 4; ++e) acc[i][j][e] = 0.f;

    const int sm  = (l & 7) << 4;       // read-side swizzle key
    const int k16 = (l >> 4) * 16;

    for (int kt = 0; kt < KBIG; kt += 64) {
        __syncthreads();
        GLDS16(A  + gA + kt,                      lA);
        GLDS16(A  + gA + kt + (size_t)64  * KBIG, lA + 64  * 128);
        GLDS16(A  + gA + kt + (size_t)128 * KBIG, lA + 128 * 128);
        GLDS16(A  + gA + kt + (size_t)192 * KBIG, lA + 192 * 128);
        GLDS16(BT + gB + kt,                      lB);
        GLDS16(BT + gB + kt + (size_t)64  * KBIG, lB + 64  * 128);
        __syncthreads();
#pragma unroll
        for (int ks = 0; ks < 2; ++ks) {
            const int ko = (ks * 64 + k16) ^ sm;
            s16x8 a[4], b[4];
#pragma unroll
            for (int mi = 0; mi < 4; ++mi)
                a[mi] = *(const s16x8*)((const char*)As + (wr * 64 + mi * 16 + lm) * 128 + ko);
#pragma unroll
            for (int ni = 0; ni < 4; ++ni)
                b[ni] = *(const s16x8*)((const char*)Bs + (wc * 64 + ni * 16 + lm) * 128 + ko);
#pragma unroll
            for (int mi = 0; mi < 4; ++mi)
#pragma unroll
                for (int ni = 0; ni < 4; ++ni)
                    MFMA16(acc[mi][ni], a[mi], b[ni]);
        }
    }

    const int rbase = m0 + wr * 64 + (l >> 4) * 4;
    const int cbase = jt + wc * 64 + lm;
#pragma unroll
    for (int mi = 0; mi < 4; ++mi)
#pragma unroll
        for (int ni = 0; ni < 4; ++ni) {
            int cc = cbase + ni * 16;
            if (cc < NREAL) {
                int bt = cc / KC;
                int c  = cc - bt * KC;
#pragma unroll
                for (int reg = 0; reg < 4; ++reg) {
                    size_t roff = (size_t)(rbase + mi * 16 + reg) * XROW;
                    float v = acc[mi][ni][reg];
                    XAhi[roff + (size_t)bt * 40 + c] = bf16hi(v);
                    if (c < 3) XAhi[roff + (size_t)bt * 40 + 36 + c] = bf16lo(v);
                }
            }
        }

    // na/rs epilogue: block-col 52, wc=1 lanes hold cols 6720+lm (hi, ni=0),
    // 6736+lm (lo, ni=1), 6752+lm (ones, ni=2; real only for lm==0).
    if (jt == 6656 && wc == 1) {
#pragma unroll
        for (int mi = 0; mi < 4; ++mi)
#pragma unroll
            for (int reg = 0; reg < 4; ++reg) {
                int r = rbase + mi * 16 + reg;
                float nav = acc[mi][0][reg] + acc[mi][1][reg];
                int rr = r & 2047;
                if (r < 2048) {
                    na_pre[rr * 16 + lm] = nav;
                    if (lm == 0) rs_pre[rr] = acc[mi][2][reg];
                } else {
                    na_dy[rr * 16 + lm] = nav;
                    if (lm == 0) rs_dy[rr] = acc[mi][2][reg];
                }
            }
    }
}

// ---------------------------------------------------------------------------
// K5: fused MFMA gates + LSTM c-recurrence, v6 (R14/R15 proven).  The LDS
// staging here is the COALESCER: 128 threads load contiguous 40-slot rows,
// LDS redistributes to fragment order (R16's direct-global variant was 2x
// slower from 16B/96B-stride scattered reads).
// ---------------------------------------------------------------------------
__global__ __launch_bounds__(512, 4) void lstm6_kernel(
    const short* __restrict__ XAhi,
    const short* __restrict__ WtBg,            // [2][WTB_SH] pre-swizzled
    const float* __restrict__ na_pre, const float* __restrict__ na_dy,
    const float* __restrict__ rs_pre, const float* __restrict__ rs_dy,
    float* __restrict__ H)
{
    __shared__ short sWtb[WTB_SH];             // 57344 B
    __shared__ short sXa[128 * KL];            // 16384 B
    const int tid = threadIdx.x;
    const int w = tid >> 6, l = tid & 63;      // 8 waves
    const int n0 = blockIdx.x * 128;
    const int b  = blockIdx.y;
    const int z  = blockIdx.z;
    const float* na = z ? na_dy : na_pre;
    const float* rs = z ? rs_dy : rs_pre;

    {
        const char* gW = (const char*)(WtBg + (size_t)z * WTB_SH);
        char* lW = (char*)sWtb;
        for (int it = 0; it < 7; ++it) {
            int base = (it * 8 + w) * 64;
            GLDS16(gW + (size_t)(base + l) * 16, lW + base * 16);
        }
    }

    const int sr = tid & 127;
    const int pp = tid >> 7;
    const short* xarow = XAhi + (size_t)(z * 2048 + n0 + sr) * XROW;
    const float* narow = na + (size_t)(n0 + sr) * 16;
    const float rsv = rs[n0 + sr];
    char* wrow = (char*)sXa + sr * 128;
    const int wswz = (sr & 7) << 4;

    const int lm = l & 15;
    const int sm = (l & 7) << 4;
    const int kof0 = ((l >> 4) * 16) ^ sm;
    const int kof1 = (64 + (l >> 4) * 16) ^ sm;
    const int an = w * 16 + lm;
    const char* xab = (const char*)sXa;
    const char* wtbb = (const char*)sWtb;
    float* Hout = H + (size_t)z * BATCH * N_NODES * MDIM;

    float cc[7][4];
#pragma unroll
    for (int mi = 0; mi < 7; ++mi)
#pragma unroll
        for (int q = 0; q < 4; ++q) cc[mi][q] = 0.f;

    // prefetch t = 0
    s16x8 ph0 = {0,0,0,0,0,0,0,0}, ph1 = ph0;
    s16x4 p0 = {0,0,0,0}, p32 = p0, plo = p0;
    {
        const int bt = b * LSEQ;
        if (pp < 2) {
            ph0 = *(const s16x8*)(xarow + bt * 40 + pp * 16);
            ph1 = *(const s16x8*)(xarow + bt * 40 + pp * 16 + 8);
        } else if (pp == 2) {
            p0  = *(const s16x4*)(xarow + bt * 40);
            p32 = *(const s16x4*)(xarow + bt * 40 + 32);
            plo = *(const s16x4*)(xarow + bt * 40 + 36);
        }
    }

    for (int t = 0; t < LSEQ; ++t) {
        __syncthreads();
        if (pp < 2) {
            *(s16x8*)(wrow + ((pp * 32 + 0)  ^ wswz)) = ph0;
            *(s16x8*)(wrow + ((pp * 32 + 16) ^ wswz)) = ph1;
        } else if (pp == 2) {
            short v[16];
            v[0] = p32[0]; v[1] = p32[1]; v[2] = p32[2];
            v[3] = plo[0]; v[4] = plo[1]; v[5] = plo[2];
            v[6] = p0[0];  v[7] = p0[1];  v[8] = p0[2];
            v[9]  = bf16hi(1.0f);
            v[10] = bf16hi(rsv);
#pragma unroll
            for (int j = 11; j < 16; ++j) v[j] = bf16hi(narow[j - 11]);
#pragma unroll
            for (int q = 0; q < 4; ++q) {
                s16x4 sv = { v[q * 4], v[q * 4 + 1], v[q * 4 + 2], v[q * 4 + 3] };
                *(s16x4*)(wrow + ((2 * 32 + q * 8) ^ wswz)) = sv;
            }
        } else {
            short v[16];
#pragma unroll
            for (int j = 0; j < 11; ++j) v[j] = bf16hi(narow[5 + j]);
            v[11] = bf16hi(1.0f);
            v[12] = bf16hi(rsv);
            v[13] = 0; v[14] = 0; v[15] = 0;
#pragma unroll
            for (int q = 0; q < 4; ++q) {
                s16x4 sv = { v[q * 4], v[q * 4 + 1], v[q * 4 + 2], v[q * 4 + 3] };
                *(s16x4*)(wrow + ((3 * 32 + q * 8) ^ wswz)) = sv;
            }
        }
        __syncthreads();

        // T14: issue t+1 loads now — latency hides under compute(t)
        if (t + 1 < LSEQ) {
            const int bt = b * LSEQ + t + 1;
            if (pp < 2) {
                ph0 = *(const s16x8*)(xarow + bt * 40 + pp * 16);
                ph1 = *(const s16x8*)(xarow + bt * 40 + pp * 16 + 8);
            } else if (pp == 2) {
                p0  = *(const s16x4*)(xarow + bt * 40);
                p32 = *(const s16x4*)(xarow + bt * 40 + 32);
                plo = *(const s16x4*)(xarow + bt * 40 + 36);
            }
        }

        s16x8 a0 = *(const s16x8*)(xab + an * 128 + kof0);
        s16x8 a1 = *(const s16x8*)(xab + an * 128 + kof1);
#pragma unroll
        for (int mi = 0; mi < 7; ++mi) {
            const char* bb = wtbb + (mi * 64 + lm) * 128;   // co=0 row; co step = +2048B
            f4 gi = {0.f, 0.f, 0.f, 0.f};
            f4 gf = gi, gg = gi;
            MFMA16(gi, a0, *(const s16x8*)(bb + kof0));
            MFMA16(gi, a1, *(const s16x8*)(bb + kof1));
            MFMA16(gf, a0, *(const s16x8*)(bb + 2048 + kof0));
            MFMA16(gf, a1, *(const s16x8*)(bb + 2048 + kof1));
            MFMA16(gg, a0, *(const s16x8*)(bb + 4096 + kof0));
            MFMA16(gg, a1, *(const s16x8*)(bb + 4096 + kof1));
#pragma unroll
            for (int q = 0; q < 4; ++q) {
                float si = sigf_(gi[q]);
                float sf = sigf_(gf[q]);
                float tg = tanhf_(gg[q]);
                cc[mi][q] = sf * cc[mi][q] + si * tg;
            }
            if (t == LSEQ - 1) {
                f4 go = {0.f, 0.f, 0.f, 0.f};
                MFMA16(go, a0, *(const s16x8*)(bb + 6144 + kof0));
                MFMA16(go, a1, *(const s16x8*)(bb + 6144 + kof1));
#pragma unroll
                for (int q = 0; q < 4; ++q) {
                    float h = sigf_(go[q]) * tanhf_(cc[mi][q]);
                    Hout[((size_t)b * N_NODES + n0 + w * 16 + (l >> 4) * 4 + q) * MDIM
                         + mi * 16 + lm] = h;
                }
            }
        }
    }
}

// ---------------------------------------------------------------------------
// K6: fused decoder, f4-vectorized H loads.
// ---------------------------------------------------------------------------
__global__ void decode_kernel(const float* __restrict__ H,
                              const float* __restrict__ Wdec,
                              const float* __restrict__ bdec,
                              const float* __restrict__ Wout,
                              const float* __restrict__ bout,
                              float* __restrict__ out)
{
    int g = blockIdx.x * 256 + threadIdx.x;   // g = b*2048 + n
    if (g >= BATCH * N_NODES) return;
    int b = g >> 11;
    int n = g & 2047;
    const f4* h0 = (const f4*)(H + (size_t)g * MDIM);
    const f4* h1 = (const f4*)(H + (size_t)BATCH * N_NODES * MDIM + (size_t)g * MDIM);
    float x[12];
#pragma unroll
    for (int o = 0; o < 12; ++o) x[o] = bdec[o];
    for (int mq = 0; mq < 28; ++mq) {
        f4 a0 = h0[mq], a1 = h1[mq];
#pragma unroll
        for (int e = 0; e < 4; ++e) {
            int m = mq * 4 + e;
#pragma unroll
            for (int o = 0; o < 12; ++o)
                x[o] += a0[e] * Wdec[(o * 3 + 0) * MDIM + m]
                      + a1[e] * (Wdec[(o * 3 + 1) * MDIM + m] + Wdec[(o * 3 + 2) * MDIM + m]);
        }
    }
#pragma unroll
    for (int p = 0; p < 12; ++p) {
        float s = bout[p];
#pragma unroll
        for (int o = 0; o < 12; ++o) s += Wout[p * 12 + o] * x[o];
        out[((size_t)b * 12 + p) * N_NODES + n] = s;
    }
}

// ---------------------------------------------------------------------------
extern "C" void kernel_launch(void* const* d_in, const int* in_sizes, int n_in,
                              void* d_out, int out_size, void* d_ws, size_t ws_size,
                              hipStream_t stream)
{
    const float* hist   = (const float*)d_in[0];
    const float* adj    = (const float*)d_in[1];
    const float* node_e = (const float*)d_in[2];
    const float* tid_e  = (const float*)d_in[3];
    const float* diw_e  = (const float*)d_in[4];
    const float* W_in   = (const float*)d_in[5];
    const float* b_in   = (const float*)d_in[6];
    const float* W_pre  = (const float*)d_in[7];
    const float* b_pre  = (const float*)d_in[8];
    const float* E_dy   = (const float*)d_in[9];
    const float* W_dy   = (const float*)d_in[10];
    const float* b_dy   = (const float*)d_in[11];
    const float* W_dec  = (const float*)d_in[12];
    const float* b_dec  = (const float*)d_in[13];
    const float* W_out  = (const float*)d_in[14];
    const float* b_out  = (const float*)d_in[15];
    float* out = (float*)d_out;

    float* ws = (float*)d_ws;
    const size_t XAHI_F = (size_t)4096 * XROW / 2;           // 15,728,640 float-equiv
    const size_t ABIG_F = (size_t)4096 * KBIG / 2;           //  4,194,304 float-equiv
    const size_t XT_F   = (size_t)NCOLS_X * KBIG / 2;        //  6,946,816 float-equiv

    short* XAhi  = (short*)ws;                // [4096][XROW] bf16
    float* AbigF = ws + XAHI_F;
    __hip_bfloat16* Abig = (__hip_bfloat16*)AbigF;
    float* H     = AbigF;                     // aliases Abig+XT (dead after gemm); 7.34M < 11.1M
    __hip_bfloat16* XTc = (__hip_bfloat16*)(ws + XAHI_F + ABIG_F);
    float* tail = ws + XAHI_F + ABIG_F + XT_F;
    float* na_pre = tail;                     tail += (size_t)N_NODES * 16;
    float* na_dy  = tail;                     tail += (size_t)N_NODES * 16;
    float* rs_pre = tail;                     tail += N_NODES;
    float* rs_dy  = tail;                     tail += N_NODES;
    short* WtBg   = (short*)tail;             // 2 * WTB_SH shorts

    // dynamic adjacency rows go straight into Abig (bf16)
    adaptive_adj_kernel<<<N_NODES, 256, 0, stream>>>(E_dy, Abig);
    wtb_pack_kernel<<<(2 * GDIM * KL + 255) / 256, 256, 0, stream>>>(
        W_in, b_in, W_pre, b_pre, W_dy, b_dy, WtBg);

    // predefined-adjacency half of Abig + full XT (features + na/rs cols)
    pack_build_kernel<<<(AQUADS + XQUADS + 255) / 256, 256, 0, stream>>>(
        adj, hist, tid_e, diw_e, node_e, Abig, XTc);

    // ONE GEMM: XAhi + na/rs (padding columns)
    gemm_bf16_kernel<<<dim3(53, 16), 512, 0, stream>>>(
        (const short*)Abig, (const short*)XTc, XAhi, na_pre, na_dy, rs_pre, rs_dy);

    // fused MFMA gates + recurrence (H overwrites dead Abig/XT region)
    lstm6_kernel<<<dim3(N_NODES / 128, BATCH, 2), 512, 0, stream>>>(
        XAhi, WtBg, na_pre, na_dy, rs_pre, rs_dy, H);

    decode_kernel<<<(BATCH * N_NODES + 255) / 256, 256, 0, stream>>>(
        H, W_dec, b_dec, W_out, b_out, out);
}